// Round 3
// baseline (173.886 us; speedup 1.0000x reference)
//
#include <hip/hip_runtime.h>

// B=262144 x C=101 fp32 -> 3 scalars.
//
// R3: kill the stage->barrier->scan serialization (m97-style vmcnt(0) drain).
//  - Persistent-ish: 512 blocks x 4 tiles (128 rows each), 128 thr/block.
//  - Double-buffered LDS + __builtin_amdgcn_global_load_lds width=16:
//      barrier(drains tile i) -> issue async prefetch tile i+1 (other buf)
//      -> scan tile i (prefetch streams underneath) -> accumulate.
//    Memory stays busy across the scan; only drain point is the next barrier.
//  - Targets for tile i+1 loaded after the prefetch issue, used next iter
//    (their wait is absorbed by the barrier -> never forces a mid-scan
//    vmcnt(0) drain of the 26 outstanding lds-loads).
//  - LDS 2*3328*16 = 106,496 B -> 1 block/CU. 2 waves/CU is fine: the plan
//    is memory-bound streaming, not latency hiding via TLP.

#define NT 128            // threads per block (= rows per tile)
#define TR 128            // rows per tile
#define NC 101
#define TILE_F4 3232      // float4 per tile (128*101/4)
#define PAD_F4 3328       // +96 float4 stray-write guard for masked tail
#define NBLK 512
#define LAMBDA_W 1000.0

__device__ __forceinline__ void gload_lds16(const float4* g, float4* l)
{
    __builtin_amdgcn_global_load_lds(
        (const __attribute__((address_space(1))) void*)g,
        (__attribute__((address_space(3))) void*)l,
        16, 0, 0);
}

// Stage one 51712-B tile: 3232 float4 = 25 full rounds of 128 lanes + 32 tail.
// Per-wave LDS dest is uniform-base + lane*16 (matches HW semantics).
__device__ __forceinline__ void prefetch_tile(const float4* __restrict__ g4,
                                              float4* l4, int tid)
{
#pragma unroll
    for (int k = 0; k < 25; ++k)
        gload_lds16(g4 + k * NT + tid, l4 + k * NT + tid);
    if (tid < 32)
        gload_lds16(g4 + 25 * NT + tid, l4 + 25 * NT + tid);
}

__global__ __launch_bounds__(NT)
void ucl_row_kernel(const float* __restrict__ x,
                    const int* __restrict__ tgt,
                    float2* __restrict__ partial,
                    int ntiles)
{
    __shared__ __align__(16) float4 buf[2][PAD_F4];   // 106,496 B
    __shared__ float red[4];

    const int tid = threadIdx.x;
    const int bid = blockIdx.x;
    const int nb  = gridDim.x;

    const int tpb   = ntiles / nb;
    const int rem   = ntiles - tpb * nb;
    const int start = bid * tpb + (bid < rem ? bid : rem);
    const int cnt   = tpb + (bid < rem ? 1 : 0);

    const float4* __restrict__ x4 = (const float4*)x;

    // Pre-loop: target row for tile 0, then async-stage tile 0 into buf0.
    int t_cur = tgt[(size_t)start * TR + tid];
    prefetch_tile(x4 + (size_t)start * TILE_F4, buf[0], tid);

    float conc = 0.f, pens = 0.f;

    for (int i = 0; i < cnt; ++i) {
        __syncthreads();   // vmcnt(0): tile i resident, t_cur resident

        if (i + 1 < cnt)
            prefetch_tile(x4 + (size_t)(start + i + 1) * TILE_F4,
                          buf[(i + 1) & 1], tid);
        int t_next = (i + 1 < cnt) ? tgt[(size_t)(start + i + 1) * TR + tid] : 0;

        // ---- scan row `tid` of tile i ----
        // LDS bank for (row,j): (101*row + j)%32 = (5*row+j)%32 -> exactly
        // 2-way per 64-lane wave = free (m136).
        const float* __restrict__ xr = (const float*)buf[i & 1] + tid * NC;
        const int t = t_cur;

        float e = __expf(xr[0]);
        float S = e, W = 0.f, Q = 0.f, pen = 0.f, ep = e;
#pragma unroll
        for (int j = 1; j < NC; ++j) {
            float e2 = __expf(xr[j]);
            float fj = (float)j;
            S += e2;
            W = fmaf(e2, fj, W);
            Q = fmaf(e2, fj * fj, Q);
            float d = ep - e2;                // ∝ p_{j-1} - p_j
            float r = ((j - 1) < t) ? d : -d;
            pen += fmaxf(r, 0.f);
            ep = e2;
        }
        float pred = W / S;
        float var  = fmaxf(fmaf(-pred, pred, Q / S), 1e-6f);
        float err  = pred - (float)t;
        conc += 0.5f * __logf(var) + err * err / (2.0f * var);
        pens += pen / S;

        t_cur = t_next;
    }

    // ---- block reduce (2 waves) ----
#pragma unroll
    for (int off = 32; off > 0; off >>= 1) {
        conc += __shfl_down(conc, off);
        pens += __shfl_down(pens, off);
    }
    if ((tid & 63) == 0) {
        red[(tid >> 6) * 2 + 0] = conc;
        red[(tid >> 6) * 2 + 1] = pens;
    }
    __syncthreads();
    if (tid == 0)
        partial[bid] = make_float2(red[0] + red[2], red[1] + red[3]);
}

__global__ __launch_bounds__(256)
void ucl_finalize(const float2* __restrict__ partial,
                  float* __restrict__ out,
                  int nblocks, double invB)
{
    const int tid = threadIdx.x;
    double c = 0.0, p = 0.0;
    for (int i = tid; i < nblocks; i += 256) {
        float2 v = partial[i];
        c += (double)v.x;
        p += (double)v.y;
    }
#pragma unroll
    for (int off = 32; off > 0; off >>= 1) {
        c += __shfl_down(c, off);
        p += __shfl_down(p, off);
    }
    __shared__ double s[8];
    if ((tid & 63) == 0) { s[(tid >> 6) * 2] = c; s[(tid >> 6) * 2 + 1] = p; }
    __syncthreads();
    if (tid == 0) {
        double C = (s[0] + s[2] + s[4] + s[6]) * invB;
        double P = (s[1] + s[3] + s[5] + s[7]) * invB * LAMBDA_W;
        out[0] = (float)(C + P);
        out[1] = (float)C;
        out[2] = (float)P;
    }
}

extern "C" void kernel_launch(void* const* d_in, const int* in_sizes, int n_in,
                              void* d_out, int out_size, void* d_ws, size_t ws_size,
                              hipStream_t stream)
{
    const float* x   = (const float*)d_in[0];
    const int*   tgt = (const int*)d_in[1];
    float* out = (float*)d_out;
    float2* partial = (float2*)d_ws;

    const int B = in_sizes[1];              // 262144
    const int ntiles = B / TR;              // 2048
    const int blocks = (ntiles < NBLK) ? ntiles : NBLK;

    hipLaunchKernelGGL(ucl_row_kernel, dim3(blocks), dim3(NT), 0, stream,
                       x, tgt, partial, ntiles);
    hipLaunchKernelGGL(ucl_finalize, dim3(1), dim3(256), 0, stream,
                       partial, out, blocks, 1.0 / (double)B);
}

// Round 4
// 154.820 us; speedup vs baseline: 1.1231x; 1.1231x over previous
//
#include <hip/hip_runtime.h>

// B=262144 x C=101 fp32 -> 3 scalars.
//
// R4: occupancy is the lever (R2: 12 waves/CU -> 45us; R3: 2 waves/CU -> 63us).
//  - 512 thr / 128-row tile, quarter-row split: LDS 51.7KB -> 3 blocks/CU
//    -> 24 waves/CU. Single-buffered stage->sync->scan; block turnover
//    provides the overlap (m114-style implicit wave-level pipelining).
//  - Penalty identity (no per-element predication):
//      pen = sum_j max(d_j,0) - e_t + e_100,  d_j = e_j - e_{j+1}
//    (from max(-d,0)-max(d,0) = -d and telescoping). -e_t applied by the
//    quarter owning col t (one predicated LDS read/row); +e_100 by q3.
//  - Staging via global_load_lds width=16 (no VGPR round trip, 7 instr).
//  - Quarter partials (S,W,Q,pen) combined by REUSING the tile LDS after a
//    barrier (separate array would cost a resident block).

#define NT 512
#define TR 128
#define NC 101
#define TILE_F4 3232      // 128*101/4
#define LAMBDA_W 1000.0

__device__ __forceinline__ void gload_lds16(const float4* g, float4* l)
{
    __builtin_amdgcn_global_load_lds(
        (const __attribute__((address_space(1))) void*)g,
        (__attribute__((address_space(3))) void*)l,
        16, 0, 0);
}

// Scan cols [LO,HI): accumulate S,W,Q over [LO,HI) and pen over d-indices
// [LO, min(HI,100)); d_{HI-1} needs e_HI (seam read). q3 adds +e_100.
// Quarter owning t subtracts e_t.
template<int LO, int HI>
__device__ __forceinline__ void scan_quarter(const float* __restrict__ xr, int t,
                                             float& S, float& W, float& Q, float& pen)
{
    float e = __expf(xr[LO]);
    S = e;
    W = (float)LO * e;
    Q = (float)(LO * LO) * e;
    pen = 0.f;
    float ep = e;
#pragma unroll
    for (int j = LO + 1; j < HI; ++j) {
        float e2 = __expf(xr[j]);
        S += e2;
        W = fmaf(e2, (float)j, W);
        Q = fmaf(e2, (float)(j * j), Q);
        pen += fmaxf(ep - e2, 0.f);
        ep = e2;
    }
    if (HI < NC) {                       // seam: d_{HI-1} = e_{HI-1} - e_HI
        float e2 = __expf(xr[HI]);
        pen += fmaxf(ep - e2, 0.f);
    } else {
        pen += ep;                       // q3: +e_100 (ep == e_100 here)
    }
    if (t >= LO && t < HI)               // owner: -e_t
        pen -= __expf(xr[t]);
}

__global__ __launch_bounds__(NT, 6)
void ucl_row_kernel(const float* __restrict__ x,
                    const int* __restrict__ tgt,
                    float2* __restrict__ partial)
{
    __shared__ __align__(16) float tile[TR * NC];   // 51712 B (reused for partials)
    __shared__ float red[4];

    const int tid = threadIdx.x;
    const int bid = blockIdx.x;
    const int r   = tid & (TR - 1);
    const int q   = tid >> 7;            // quarter index 0..3 (wave-uniform)

    // ---- stage tile: 3232 float4 = 6*512 + 160, direct-to-LDS ----
    {
        const float4* __restrict__ g4 =
            (const float4*)(x + (size_t)bid * (TR * NC));
        float4* l4 = (float4*)tile;
#pragma unroll
        for (int k = 0; k < 6; ++k)
            gload_lds16(g4 + k * NT + tid, l4 + k * NT + tid);
        if (tid < TILE_F4 - 6 * NT)      // 160-wide tail, exec-masked
            gload_lds16(g4 + 6 * NT + tid, l4 + 6 * NT + tid);
    }
    const int t = tgt[(size_t)bid * TR + r];
    __syncthreads();                      // vmcnt(0): tile + t resident

    // ---- quarter scan. Bank (5r + j) % 32 over 64 consecutive r = 2-way free.
    const float* __restrict__ xr = tile + r * NC;
    float S, W, Q, pen;
    if      (q == 0) scan_quarter< 0,  26>(xr, t, S, W, Q, pen);
    else if (q == 1) scan_quarter<26,  51>(xr, t, S, W, Q, pen);
    else if (q == 2) scan_quarter<51,  76>(xr, t, S, W, Q, pen);
    else             scan_quarter<76, 101>(xr, t, S, W, Q, pen);

    __syncthreads();                      // all tile reads done -> safe to reuse
    // partials: row stride 20 floats (uniform bank coverage), 16B-aligned
    {
        float4* p4 = (float4*)(tile + r * 20 + q * 4);   // max 2559 < 12928
        *p4 = make_float4(S, W, Q, pen);
    }
    __syncthreads();

    // ---- combine + epilogue (quarter 0 = waves 0,1) ----
    float conc = 0.f, pens = 0.f;
    if (q == 0) {
        const float4* p4 = (const float4*)(tile + r * 20);
        float4 a = p4[0], b = p4[1], c = p4[2], d = p4[3];
        float Sf = a.x + b.x + c.x + d.x;
        float Wf = a.y + b.y + c.y + d.y;
        float Qf = a.z + b.z + c.z + d.z;
        float Pf = a.w + b.w + c.w + d.w;
        float pred = Wf / Sf;
        float var  = fmaxf(fmaf(-pred, pred, Qf / Sf), 1e-6f);
        float err  = pred - (float)t;
        conc = 0.5f * __logf(var) + err * err / (2.0f * var);
        pens = Pf / Sf;
    }

    // ---- block reduce (waves 2..7 contribute zeros) ----
#pragma unroll
    for (int off = 32; off > 0; off >>= 1) {
        conc += __shfl_down(conc, off);
        pens += __shfl_down(pens, off);
    }
    if (tid < 2 * TR && (tid & 63) == 0) {
        red[(tid >> 6) * 2 + 0] = conc;
        red[(tid >> 6) * 2 + 1] = pens;
    }
    __syncthreads();
    if (tid == 0)
        partial[bid] = make_float2(red[0] + red[2], red[1] + red[3]);
}

__global__ __launch_bounds__(256)
void ucl_finalize(const float2* __restrict__ partial,
                  float* __restrict__ out,
                  int nblocks, double invB)
{
    const int tid = threadIdx.x;
    double c = 0.0, p = 0.0;
    for (int i = tid; i < nblocks; i += 256) {
        float2 v = partial[i];
        c += (double)v.x;
        p += (double)v.y;
    }
#pragma unroll
    for (int off = 32; off > 0; off >>= 1) {
        c += __shfl_down(c, off);
        p += __shfl_down(p, off);
    }
    __shared__ double s[8];
    if ((tid & 63) == 0) { s[(tid >> 6) * 2] = c; s[(tid >> 6) * 2 + 1] = p; }
    __syncthreads();
    if (tid == 0) {
        double C = (s[0] + s[2] + s[4] + s[6]) * invB;
        double P = (s[1] + s[3] + s[5] + s[7]) * invB * LAMBDA_W;
        out[0] = (float)(C + P);
        out[1] = (float)C;
        out[2] = (float)P;
    }
}

extern "C" void kernel_launch(void* const* d_in, const int* in_sizes, int n_in,
                              void* d_out, int out_size, void* d_ws, size_t ws_size,
                              hipStream_t stream)
{
    const float* x   = (const float*)d_in[0];
    const int*   tgt = (const int*)d_in[1];
    float* out = (float*)d_out;
    float2* partial = (float2*)d_ws;

    const int B = in_sizes[1];            // 262144
    const int blocks = B / TR;            // 2048

    hipLaunchKernelGGL(ucl_row_kernel, dim3(blocks), dim3(NT), 0, stream,
                       x, tgt, partial);
    hipLaunchKernelGGL(ucl_finalize, dim3(1), dim3(256), 0, stream,
                       partial, out, blocks, 1.0 / (double)B);
}